// Round 1
// baseline (58.540 us; speedup 1.0000x reference)
//
#include <hip/hip_runtime.h>

#define NB 2
#define NN 1024
#define DD 128
#define NROWS (NB*NN)   // 2048 flat rows

#define NEG_INF (-__builtin_huge_valf())

// ---------------- Kernel A: msg1 = F@w1+b1 ; msg2 = F@w2+b2 ; h1 = F@wo+bo ----
// grid 256 blocks x 256 thr; each block handles 8 rows (features flat 2048x128).
__global__ __launch_bounds__(256) void kA_lin3(
    const float* __restrict__ feat,
    const float* __restrict__ w1, const float* __restrict__ b1,
    const float* __restrict__ w2, const float* __restrict__ b2,
    const float* __restrict__ wo, const float* __restrict__ bo,
    float* __restrict__ msg1, float* __restrict__ msg2, float* __restrict__ h1)
{
    __shared__ float sf[8][128];
    const int tid = threadIdx.x;
    const int rb = blockIdx.x * 8;
    {   // stage 8x128 floats = 256 float4s, one per thread
        int r = tid >> 5;            // 32 float4 per row
        int c = (tid & 31) * 4;
        *reinterpret_cast<float4*>(&sf[r][c]) =
            *reinterpret_cast<const float4*>(feat + (size_t)(rb + r) * 128 + c);
    }
    __syncthreads();
    const int m  = tid & 127;
    const int rh = tid >> 7;         // 0..1 -> rows rh*4 + 0..3
    float a1[4] = {0,0,0,0}, a2[4] = {0,0,0,0}, ao[4] = {0,0,0,0};
    #pragma unroll 4
    for (int k = 0; k < 128; ++k) {
        float wv1 = w1[k*128 + m];
        float wv2 = w2[k*128 + m];
        float wvo = wo[k*128 + m];
        #pragma unroll
        for (int r = 0; r < 4; ++r) {
            float f = sf[rh*4 + r][k];     // wave-uniform -> LDS broadcast
            a1[r] = fmaf(f, wv1, a1[r]);
            a2[r] = fmaf(f, wv2, a2[r]);
            ao[r] = fmaf(f, wvo, ao[r]);
        }
    }
    const float bb1 = b1[m], bb2 = b2[m], bbo = bo[m];
    #pragma unroll
    for (int r = 0; r < 4; ++r) {
        size_t row = rb + rh*4 + r;
        msg1[row*128 + m] = a1[r] + bb1;
        msg2[row*128 + m] = a2[r] + bb2;
        h1  [row*128 + m] = ao[r] + bbo;
    }
}

// ---------------- Kernel B: partial masked max over i-range ------------------
// out_partial[t][b][j][m] = max_{i in range_t, adj[b,i,j]!=0} msg2[b,i,m]  (-inf if none)
// grid (jt=16, it=ISPLIT, b=2), block 256.
// Thread: mg = tid&7 (16 m's), jl = tid>>3 (j0+jl and j0+32+jl) -> msg2 regs reused for 2 j's.
template<int ISPLIT>
__global__ __launch_bounds__(256) void kB_maxred(
    const float* __restrict__ adj, const float* __restrict__ msg2,
    float* __restrict__ partial)
{
    __shared__ float sm2[32][128];
    __shared__ float sadj[32][64];
    const int tid = threadIdx.x;
    const int jt = blockIdx.x, it = blockIdx.y, b = blockIdx.z;
    const int j0 = jt * 64;
    const int ilen = NN / ISPLIT;
    const int i0 = it * ilen;
    const int mg = tid & 7;
    const int jl = tid >> 3;

    float acc0[16], acc1[16];
    #pragma unroll
    for (int t = 0; t < 16; ++t) { acc0[t] = NEG_INF; acc1[t] = NEG_INF; }

    for (int ic = 0; ic < ilen; ic += 32) {
        // stage msg2 tile [32][128]
        #pragma unroll
        for (int k = 0; k < 4; ++k) {
            int idx = tid + k*256;
            int r = idx >> 5, c = (idx & 31) * 4;
            *reinterpret_cast<float4*>(&sm2[r][c]) =
                *reinterpret_cast<const float4*>(msg2 + (size_t)(b*NN + i0 + ic + r)*128 + c);
        }
        // stage adj tile [32][64]
        #pragma unroll
        for (int k = 0; k < 2; ++k) {
            int idx = tid + k*256;
            int r = idx >> 4, c = (idx & 15) * 4;
            *reinterpret_cast<float4*>(&sadj[r][c]) =
                *reinterpret_cast<const float4*>(adj + (size_t)b*NN*NN + (size_t)(i0 + ic + r)*NN + j0 + c);
        }
        __syncthreads();
        #pragma unroll 4
        for (int i = 0; i < 32; ++i) {
            const bool on0 = (sadj[i][jl]      != 0.0f);
            const bool on1 = (sadj[i][32 + jl] != 0.0f);
            #pragma unroll
            for (int q = 0; q < 4; ++q) {
                float4 v = *reinterpret_cast<const float4*>(&sm2[i][mg*16 + q*4]);
                const float* vp = reinterpret_cast<const float*>(&v);
                #pragma unroll
                for (int w = 0; w < 4; ++w) {
                    float t0 = on0 ? vp[w] : NEG_INF;
                    float t1 = on1 ? vp[w] : NEG_INF;
                    acc0[q*4+w] = fmaxf(acc0[q*4+w], t0);
                    acc1[q*4+w] = fmaxf(acc1[q*4+w], t1);
                }
            }
        }
        __syncthreads();
    }
    float* p0 = partial + ((size_t)(it*2 + b)*NN + (j0 + jl))*128 + mg*16;
    float* p1 = partial + ((size_t)(it*2 + b)*NN + (j0 + 32 + jl))*128 + mg*16;
    #pragma unroll
    for (int q = 0; q < 4; ++q) {
        *reinterpret_cast<float4*>(p0 + q*4) = make_float4(acc0[q*4], acc0[q*4+1], acc0[q*4+2], acc0[q*4+3]);
        *reinterpret_cast<float4*>(p1 + q*4) = make_float4(acc1[q*4], acc1[q*4+1], acc1[q*4+2], acc1[q*4+3]);
    }
}

// ---------------- Kernel C: combine partials + relu + MLP + h1 add -----------
// grid 256 blocks x 256 thr; 8 rows per block.
template<int ISPLIT>
__global__ __launch_bounds__(256) void kC_mlp(
    const float* __restrict__ msg1, const float* __restrict__ h1,
    const float* __restrict__ partial,
    const float* __restrict__ wm0, const float* __restrict__ bm0,
    const float* __restrict__ wm1, const float* __restrict__ bm1,
    const float* __restrict__ wm2, const float* __restrict__ bm2,
    const float* __restrict__ wm3, const float* __restrict__ bm3,
    float* __restrict__ out)
{
    __shared__ float sx[8][128];
    __shared__ float sh0[8][32];
    __shared__ float sh1[8][64];
    __shared__ float sh2[8][64];
    const int tid = threadIdx.x;
    const int rb = blockIdx.x * 8;

    // x = relu(msg1 + max_t partial_t)
    #pragma unroll
    for (int k = 0; k < 4; ++k) {
        int idx = tid + k*256;
        int r = idx >> 7, c = idx & 127;
        size_t row = rb + r;                 // row = b*NN + j
        float p = NEG_INF;
        #pragma unroll
        for (int t = 0; t < ISPLIT; ++t)
            p = fmaxf(p, partial[((size_t)t*2*NN + row)*128 + c]);
        float v = msg1[row*128 + c] + p;     // -inf propagates -> relu 0
        sx[r][c] = fmaxf(v, 0.0f);
    }
    __syncthreads();
    // L0: 128 -> 32
    {
        int r = tid >> 5, c = tid & 31;
        float acc = bm0[c];
        #pragma unroll 8
        for (int k = 0; k < 128; ++k) acc = fmaf(sx[r][k], wm0[k*32 + c], acc);
        sh0[r][c] = fmaxf(acc, 0.0f);
    }
    __syncthreads();
    // L1: 32 -> 64, 2 rows/thread
    {
        int c = tid & 63, rq = tid >> 6;
        float acc0 = bm1[c], acc1 = bm1[c];
        #pragma unroll
        for (int k = 0; k < 32; ++k) {
            float w = wm1[k*64 + c];
            acc0 = fmaf(sh0[rq*2][k],   w, acc0);
            acc1 = fmaf(sh0[rq*2+1][k], w, acc1);
        }
        sh1[rq*2][c]   = fmaxf(acc0, 0.0f);
        sh1[rq*2+1][c] = fmaxf(acc1, 0.0f);
    }
    __syncthreads();
    // L2: 64 -> 64, 2 rows/thread
    {
        int c = tid & 63, rq = tid >> 6;
        float acc0 = bm2[c], acc1 = bm2[c];
        #pragma unroll 8
        for (int k = 0; k < 64; ++k) {
            float w = wm2[k*64 + c];
            acc0 = fmaf(sh1[rq*2][k],   w, acc0);
            acc1 = fmaf(sh1[rq*2+1][k], w, acc1);
        }
        sh2[rq*2][c]   = fmaxf(acc0, 0.0f);
        sh2[rq*2+1][c] = fmaxf(acc1, 0.0f);
    }
    __syncthreads();
    // L3: 64 -> 128, 4 rows/thread, + h1, no relu
    {
        int c = tid & 127, rq = tid >> 7;
        float acc[4];
        const float bb = bm3[c];
        #pragma unroll
        for (int r = 0; r < 4; ++r) acc[r] = bb;
        #pragma unroll 8
        for (int k = 0; k < 64; ++k) {
            float w = wm3[k*128 + c];
            #pragma unroll
            for (int r = 0; r < 4; ++r)
                acc[r] = fmaf(sh2[rq*4 + r][k], w, acc[r]);
        }
        #pragma unroll
        for (int r = 0; r < 4; ++r) {
            size_t row = rb + rq*4 + r;
            out[row*128 + c] = h1[row*128 + c] + acc[r];
        }
    }
}

extern "C" void kernel_launch(void* const* d_in, const int* in_sizes, int n_in,
                              void* d_out, int out_size, void* d_ws, size_t ws_size,
                              hipStream_t stream)
{
    const float* feat = (const float*)d_in[0];
    // d_in[1] = e_features (unused), d_in[2] = g_features (unused)
    const float* adj  = (const float*)d_in[3];
    const float* w1 = (const float*)d_in[4];   const float* b1 = (const float*)d_in[5];
    const float* w2 = (const float*)d_in[6];   const float* b2 = (const float*)d_in[7];
    const float* wo = (const float*)d_in[8];   const float* bo = (const float*)d_in[9];
    const float* wm0 = (const float*)d_in[10]; const float* bm0 = (const float*)d_in[11];
    const float* wm1 = (const float*)d_in[12]; const float* bm1 = (const float*)d_in[13];
    const float* wm2 = (const float*)d_in[14]; const float* bm2 = (const float*)d_in[15];
    const float* wm3 = (const float*)d_in[16]; const float* bm3 = (const float*)d_in[17];
    float* out = (float*)d_out;

    float* ws = (float*)d_ws;
    const size_t MAT = (size_t)NROWS * 128;   // 262144 floats
    float* msg1 = ws;
    float* msg2 = ws + MAT;
    float* h1   = ws + 2*MAT;
    float* partial = ws + 3*MAT;

    // choose i-split so workspace fits: need (3 + ISPLIT) * MAT floats
    int isplit = 1;
    if      (ws_size >= (3 + 8) * MAT * 4) isplit = 8;
    else if (ws_size >= (3 + 4) * MAT * 4) isplit = 4;
    else if (ws_size >= (3 + 2) * MAT * 4) isplit = 2;

    kA_lin3<<<256, 256, 0, stream>>>(feat, w1, b1, w2, b2, wo, bo, msg1, msg2, h1);

    dim3 gb(16, isplit, 2);
    switch (isplit) {
    case 8:
        kB_maxred<8><<<gb, 256, 0, stream>>>(adj, msg2, partial);
        kC_mlp<8><<<256, 256, 0, stream>>>(msg1, h1, partial,
            wm0,bm0,wm1,bm1,wm2,bm2,wm3,bm3, out);
        break;
    case 4:
        kB_maxred<4><<<gb, 256, 0, stream>>>(adj, msg2, partial);
        kC_mlp<4><<<256, 256, 0, stream>>>(msg1, h1, partial,
            wm0,bm0,wm1,bm1,wm2,bm2,wm3,bm3, out);
        break;
    case 2:
        kB_maxred<2><<<gb, 256, 0, stream>>>(adj, msg2, partial);
        kC_mlp<2><<<256, 256, 0, stream>>>(msg1, h1, partial,
            wm0,bm0,wm1,bm1,wm2,bm2,wm3,bm3, out);
        break;
    default:
        kB_maxred<1><<<gb, 256, 0, stream>>>(adj, msg2, partial);
        kC_mlp<1><<<256, 256, 0, stream>>>(msg1, h1, partial,
            wm0,bm0,wm1,bm1,wm2,bm2,wm3,bm3, out);
        break;
    }
}

// Round 2
// 46.640 us; speedup vs baseline: 1.2551x; 1.2551x over previous
//
#include <hip/hip_runtime.h>

#define NB 2
#define NN 1024
#define NROWS (NB*NN)   // 2048 flat rows

#define NEG_INF (-__builtin_huge_valf())

__device__ __forceinline__ float orf(float v, unsigned int m) {
    return __uint_as_float(__float_as_uint(v) | m);
}

// ---------------- Kernel A: msg1 = F@w1+b1 ; msg2 = F@w2+b2 ; h1 = F@wo+bo ----
// grid 256 blocks x 256 thr; each block handles 8 rows (features flat 2048x128).
__global__ __launch_bounds__(256) void kA_lin3(
    const float* __restrict__ feat,
    const float* __restrict__ w1, const float* __restrict__ b1,
    const float* __restrict__ w2, const float* __restrict__ b2,
    const float* __restrict__ wo, const float* __restrict__ bo,
    float* __restrict__ msg1, float* __restrict__ msg2, float* __restrict__ h1)
{
    __shared__ float sf[8][128];
    const int tid = threadIdx.x;
    const int rb = blockIdx.x * 8;
    {
        int r = tid >> 5;
        int c = (tid & 31) * 4;
        *reinterpret_cast<float4*>(&sf[r][c]) =
            *reinterpret_cast<const float4*>(feat + (size_t)(rb + r) * 128 + c);
    }
    __syncthreads();
    const int m  = tid & 127;
    const int rh = tid >> 7;
    float a1[4] = {0,0,0,0}, a2[4] = {0,0,0,0}, ao[4] = {0,0,0,0};
    #pragma unroll 4
    for (int k = 0; k < 128; ++k) {
        float wv1 = w1[k*128 + m];
        float wv2 = w2[k*128 + m];
        float wvo = wo[k*128 + m];
        #pragma unroll
        for (int r = 0; r < 4; ++r) {
            float f = sf[rh*4 + r][k];
            a1[r] = fmaf(f, wv1, a1[r]);
            a2[r] = fmaf(f, wv2, a2[r]);
            ao[r] = fmaf(f, wvo, ao[r]);
        }
    }
    const float bb1 = b1[m], bb2 = b2[m], bbo = bo[m];
    #pragma unroll
    for (int r = 0; r < 4; ++r) {
        size_t row = rb + rh*4 + r;
        msg1[row*128 + m] = a1[r] + bb1;
        msg2[row*128 + m] = a2[r] + bb2;
        h1  [row*128 + m] = ao[r] + bbo;
    }
}

// ---------------- Kernel B: partial masked max over i-range ------------------
// partial[t][b][j][m] = max_{i in range_t, adj[b,i,j]!=0} msg2[b,i,m]  (-inf if none)
// grid (jt=16, it=ISPLIT, z=4: b=z>>1, mt=z&1), block 256. 2 blocks/CU.
// Thread: mg = tid&7 -> 8 m's (m0+mg*8..+8), jl = tid>>3 -> j's (j0+jl, j0+32+jl).
// Inner: NaN-poison masks from LDS, v_or + v_max3 over i-pairs = 1.5 ops/elem.
template<int ISPLIT>
__global__ __launch_bounds__(256) void kB_maxred(
    const float* __restrict__ adj, const float* __restrict__ msg2,
    float* __restrict__ partial)
{
    __shared__ float sm2[128][64];          // [i][m] 32 KB
    __shared__ unsigned int smk[128][68];   // [i][j] NaN-poison masks, padded stride
    const int tid = threadIdx.x;
    const int jt = blockIdx.x;
    const int it = blockIdx.y;
    const int mt = blockIdx.z & 1;
    const int b  = blockIdx.z >> 1;
    const int j0 = jt * 64, m0 = mt * 64;
    const int ilen = NN / ISPLIT;
    const int i0 = it * ilen;
    const int mg = tid & 7;
    const int jl = tid >> 3;

    float a0[8], a1[8];
    #pragma unroll
    for (int w = 0; w < 8; ++w) { a0[w] = NEG_INF; a1[w] = NEG_INF; }

    for (int ic = 0; ic < ilen; ic += 128) {
        if (ic) __syncthreads();
        {
            // stage msg2 tile [128][64]
            const float* gp = msg2 + ((size_t)(b*NN + i0 + ic))*128 + m0;
            #pragma unroll
            for (int k = 0; k < 8; ++k) {
                int idx = tid + k*256;
                int r = idx >> 4, c = (idx & 15) * 4;
                *reinterpret_cast<float4*>(&sm2[r][c]) =
                    *reinterpret_cast<const float4*>(gp + (size_t)r*128 + c);
            }
            // stage adj tile [128][64] -> NaN-poison masks
            const float* ga = adj + (size_t)b*NN*NN + (size_t)(i0 + ic)*NN + j0;
            #pragma unroll
            for (int k = 0; k < 8; ++k) {
                int idx = tid + k*256;
                int r = idx >> 4, c = (idx & 15) * 4;
                float4 av = *reinterpret_cast<const float4*>(ga + (size_t)r*NN + c);
                uint4 mk;
                mk.x = (av.x != 0.f) ? 0u : 0xFFC00000u;
                mk.y = (av.y != 0.f) ? 0u : 0xFFC00000u;
                mk.z = (av.z != 0.f) ? 0u : 0xFFC00000u;
                mk.w = (av.w != 0.f) ? 0u : 0xFFC00000u;
                *reinterpret_cast<uint4*>(&smk[r][c]) = mk;
            }
        }
        __syncthreads();
        const float* vr = &sm2[0][mg*8];
        const unsigned int* mrA = &smk[0][jl];
        const unsigned int* mrB = &smk[0][32 + jl];
        #pragma unroll 4
        for (int i = 0; i < 128; i += 2) {
            float4 va = *reinterpret_cast<const float4*>(vr + i*64);
            float4 vb = *reinterpret_cast<const float4*>(vr + i*64 + 4);
            float4 vc = *reinterpret_cast<const float4*>(vr + (i+1)*64);
            float4 vd = *reinterpret_cast<const float4*>(vr + (i+1)*64 + 4);
            unsigned int mA0 = mrA[i*68], mA1 = mrA[(i+1)*68];
            unsigned int mB0 = mrB[i*68], mB1 = mrB[(i+1)*68];
            float v0[8] = {va.x,va.y,va.z,va.w,vb.x,vb.y,vb.z,vb.w};
            float v1[8] = {vc.x,vc.y,vc.z,vc.w,vd.x,vd.y,vd.z,vd.w};
            #pragma unroll
            for (int w = 0; w < 8; ++w) {
                // poisoned operand is quiet NaN -> dropped by IEEE max
                a0[w] = fmaxf(fmaxf(a0[w], orf(v0[w], mA0)), orf(v1[w], mA1));
                a1[w] = fmaxf(fmaxf(a1[w], orf(v0[w], mB0)), orf(v1[w], mB1));
            }
        }
    }
    float* p0 = partial + ((size_t)(it*2 + b)*NN + (size_t)(j0 + jl))*128 + m0 + mg*8;
    float* p1 = partial + ((size_t)(it*2 + b)*NN + (size_t)(j0 + 32 + jl))*128 + m0 + mg*8;
    *reinterpret_cast<float4*>(p0)     = make_float4(a0[0],a0[1],a0[2],a0[3]);
    *reinterpret_cast<float4*>(p0 + 4) = make_float4(a0[4],a0[5],a0[6],a0[7]);
    *reinterpret_cast<float4*>(p1)     = make_float4(a1[0],a1[1],a1[2],a1[3]);
    *reinterpret_cast<float4*>(p1 + 4) = make_float4(a1[4],a1[5],a1[6],a1[7]);
}

// ---------------- Kernel C: combine partials + relu + MLP + h1 add -----------
// grid 512 blocks x 256 thr; 4 rows per block (2 blocks/CU).
template<int ISPLIT>
__global__ __launch_bounds__(256) void kC_mlp(
    const float* __restrict__ msg1, const float* __restrict__ h1,
    const float* __restrict__ partial,
    const float* __restrict__ wm0, const float* __restrict__ bm0,
    const float* __restrict__ wm1, const float* __restrict__ bm1,
    const float* __restrict__ wm2, const float* __restrict__ bm2,
    const float* __restrict__ wm3, const float* __restrict__ bm3,
    float* __restrict__ out)
{
    __shared__ float sx[4][128];
    __shared__ float sh0[4][32];
    __shared__ float sh1[4][64];
    __shared__ float sh2[4][64];
    const int tid = threadIdx.x;
    const int rb = blockIdx.x * 4;

    if (tid < 128) {
        int r = tid >> 5, c = (tid & 31) * 4;
        size_t row = rb + r;
        float4 p = make_float4(NEG_INF, NEG_INF, NEG_INF, NEG_INF);
        #pragma unroll
        for (int t = 0; t < ISPLIT; ++t) {
            float4 q = *reinterpret_cast<const float4*>(
                partial + ((size_t)t*NROWS + row)*128 + c);
            p.x = fmaxf(p.x, q.x); p.y = fmaxf(p.y, q.y);
            p.z = fmaxf(p.z, q.z); p.w = fmaxf(p.w, q.w);
        }
        float4 m1 = *reinterpret_cast<const float4*>(msg1 + row*128 + c);
        sx[r][c+0] = fmaxf(m1.x + p.x, 0.f);   // -inf propagates -> relu 0
        sx[r][c+1] = fmaxf(m1.y + p.y, 0.f);
        sx[r][c+2] = fmaxf(m1.z + p.z, 0.f);
        sx[r][c+3] = fmaxf(m1.w + p.w, 0.f);
    }
    __syncthreads();
    if (tid < 128) {   // L0: 128 -> 32
        int r = tid >> 5, c = tid & 31;
        float acc = bm0[c];
        #pragma unroll 8
        for (int k = 0; k < 128; ++k) acc = fmaf(sx[r][k], wm0[k*32 + c], acc);
        sh0[r][c] = fmaxf(acc, 0.f);
    }
    __syncthreads();
    {   // L1: 32 -> 64
        int r = tid >> 6, c = tid & 63;
        float acc = bm1[c];
        #pragma unroll
        for (int k = 0; k < 32; ++k) acc = fmaf(sh0[r][k], wm1[k*64 + c], acc);
        sh1[r][c] = fmaxf(acc, 0.f);
    }
    __syncthreads();
    {   // L2: 64 -> 64
        int r = tid >> 6, c = tid & 63;
        float acc = bm2[c];
        #pragma unroll 8
        for (int k = 0; k < 64; ++k) acc = fmaf(sh1[r][k], wm2[k*64 + c], acc);
        sh2[r][c] = fmaxf(acc, 0.f);
    }
    __syncthreads();
    {   // L3: 64 -> 128, 2 rows/thread, + h1, no relu
        int rq = tid >> 7, c = tid & 127;
        float acc0 = bm3[c], acc1 = bm3[c];
        #pragma unroll 8
        for (int k = 0; k < 64; ++k) {
            float w = wm3[k*128 + c];
            acc0 = fmaf(sh2[rq*2][k],   w, acc0);
            acc1 = fmaf(sh2[rq*2+1][k], w, acc1);
        }
        size_t r0 = rb + rq*2, r1 = rb + rq*2 + 1;
        out[r0*128 + c] = h1[r0*128 + c] + acc0;
        out[r1*128 + c] = h1[r1*128 + c] + acc1;
    }
}

extern "C" void kernel_launch(void* const* d_in, const int* in_sizes, int n_in,
                              void* d_out, int out_size, void* d_ws, size_t ws_size,
                              hipStream_t stream)
{
    const float* feat = (const float*)d_in[0];
    // d_in[1] = e_features (unused), d_in[2] = g_features (unused)
    const float* adj  = (const float*)d_in[3];
    const float* w1 = (const float*)d_in[4];   const float* b1 = (const float*)d_in[5];
    const float* w2 = (const float*)d_in[6];   const float* b2 = (const float*)d_in[7];
    const float* wo = (const float*)d_in[8];   const float* bo = (const float*)d_in[9];
    const float* wm0 = (const float*)d_in[10]; const float* bm0 = (const float*)d_in[11];
    const float* wm1 = (const float*)d_in[12]; const float* bm1 = (const float*)d_in[13];
    const float* wm2 = (const float*)d_in[14]; const float* bm2 = (const float*)d_in[15];
    const float* wm3 = (const float*)d_in[16]; const float* bm3 = (const float*)d_in[17];
    float* out = (float*)d_out;

    float* ws = (float*)d_ws;
    const size_t MAT = (size_t)NROWS * 128;   // 262144 floats
    float* msg1 = ws;
    float* msg2 = ws + MAT;
    float* h1   = ws + 2*MAT;
    float* partial = ws + 3*MAT;

    int isplit = 1;
    if      (ws_size >= (3 + 8) * MAT * 4) isplit = 8;
    else if (ws_size >= (3 + 4) * MAT * 4) isplit = 4;
    else if (ws_size >= (3 + 2) * MAT * 4) isplit = 2;

    kA_lin3<<<256, 256, 0, stream>>>(feat, w1, b1, w2, b2, wo, bo, msg1, msg2, h1);

    dim3 gb(16, isplit, 4);
    switch (isplit) {
    case 8:
        kB_maxred<8><<<gb, 256, 0, stream>>>(adj, msg2, partial);
        kC_mlp<8><<<512, 256, 0, stream>>>(msg1, h1, partial,
            wm0,bm0,wm1,bm1,wm2,bm2,wm3,bm3, out);
        break;
    case 4:
        kB_maxred<4><<<gb, 256, 0, stream>>>(adj, msg2, partial);
        kC_mlp<4><<<512, 256, 0, stream>>>(msg1, h1, partial,
            wm0,bm0,wm1,bm1,wm2,bm2,wm3,bm3, out);
        break;
    case 2:
        kB_maxred<2><<<gb, 256, 0, stream>>>(adj, msg2, partial);
        kC_mlp<2><<<512, 256, 0, stream>>>(msg1, h1, partial,
            wm0,bm0,wm1,bm1,wm2,bm2,wm3,bm3, out);
        break;
    default:
        kB_maxred<1><<<gb, 256, 0, stream>>>(adj, msg2, partial);
        kC_mlp<1><<<512, 256, 0, stream>>>(msg1, h1, partial,
            wm0,bm0,wm1,bm1,wm2,bm2,wm3,bm3, out);
        break;
    }
}